// Round 8
// baseline (2522.625 us; speedup 1.0000x reference)
//
#include <hip/hip_runtime.h>
#include <math.h>

#define BATCH 4096
#define LDIM 1024
#define HDIM 2048
#define ODIM 512
#define GDIM 3072   // 3*LDIM
#define JDIM 1536   // IDIM+ODIM == LDIM+ODIM
#define INNER 4
#define OUTER 8

using f16 = _Float16;
using f16x4 = __attribute__((ext_vector_type(4))) _Float16;
using f16x8 = __attribute__((ext_vector_type(8))) _Float16;
using f32x4 = __attribute__((ext_vector_type(4))) float;

typedef __attribute__((address_space(3))) void lds_void;
typedef __attribute__((address_space(1))) void glob_void;

__device__ __forceinline__ void gload16(const void* g, void* l) {
  __builtin_amdgcn_global_load_lds((const glob_void*)g, (lds_void*)l, 16, 0, 0);
}

#define MFMA16(a, b, c) __builtin_amdgcn_mfma_f32_16x16x32_f16(a, b, c, 0, 0, 0)
// counted vmcnt wait: keeps prefetch loads in flight across raw s_barrier
#define WAIT_VM(N) asm volatile("s_waitcnt vmcnt(" #N ")" ::: "memory")
#define SBAR asm volatile("s_barrier" ::: "memory")

__device__ __forceinline__ float fast_sigmoid(float x) {
  return __builtin_amdgcn_rcpf(1.0f + __expf(-x));
}
__device__ __forceinline__ float fast_tanh(float x) {
  return 1.0f - 2.0f * __builtin_amdgcn_rcpf(1.0f + __expf(2.0f * x));
}

// fp32 -> fp16 (RTN), n4 = elems/4
__global__ __launch_bounds__(256) void convert_w(const float* __restrict__ src,
                                                 f16* __restrict__ dst, int n4) {
  int i = blockIdx.x * 256 + threadIdx.x;
  if (i >= n4) return;
  float4 v = ((const float4*)src)[i];
  f16x4 d = {(f16)v.x, (f16)v.y, (f16)v.z, (f16)v.w};
  *(f16x4*)&dst[(size_t)i * 4] = d;
}

// W2 = W_ih[:, 1024:1536] fp32 -> f16 contiguous [3072][512]
__global__ __launch_bounds__(256) void convert_w2(const float* __restrict__ src,
                                                  f16* __restrict__ dst) {
  int idx = blockIdx.x * 256 + threadIdx.x;  // over 3072*128 float4s
  if (idx >= GDIM * 128) return;
  int row = idx >> 7, c4 = idx & 127;
  float4 v = *(const float4*)&src[(size_t)row * JDIM + 1024 + c4 * 4];
  f16x4 d = {(f16)v.x, (f16)v.y, (f16)v.z, (f16)v.w};
  *(f16x4*)&dst[(size_t)row * 512 + c4 * 4] = d;
}

// ============================================================================
// 8-phase 256x256 fp16 GEMM (best measured for K=1536: 65.8us in R6).
// 512 threads = 8 waves (2M x 4N); wave output 128x64 = acc[8][4] frags.
// BK=64 in 2 K-halves; LDS = 128 KB; vmcnt(4)+barrier at phases 0/2.
// EPI 1: joint head relu: n<2048 -> h1 f16 (bias), else h2 f16 (bias2)
// ============================================================================
template <int EPI>
__global__ __launch_bounds__(512, 1) void gemm_256(
    const f16* __restrict__ A, const f16* __restrict__ W,
    const float* __restrict__ bias, const float* __restrict__ bias2,
    const f16* __restrict__ Xb,
    f16* __restrict__ Ch, f16* __restrict__ Cf, int N, int K, int lda, int ldw) {
  __shared__ f16 sA[2 * 2 * 256 * 32];  // 64 KB
  __shared__ f16 sW[2 * 2 * 256 * 32];  // 64 KB
  const int tid = threadIdx.x;
  const int w = tid >> 6, lane = tid & 63;
  const int wm = w >> 2, wn = w & 3;
  const int fr = lane & 15, quad = lane >> 4;
  const int nb = N >> 8;
  const int m0 = (blockIdx.x / nb) * 256, n0 = (blockIdx.x % nb) * 256;

  const int swz_src = (((tid & 3) ^ ((tid >> 3) & 3)) * 8);
  const f16* pAst = A + (size_t)(m0 + (tid >> 2)) * lda + swz_src;
  const f16* pWst = W + (size_t)(n0 + (tid >> 2)) * ldw + swz_src;
  const size_t h128a = (size_t)128 * lda;
  const size_t h128w = (size_t)128 * ldw;
  const int ldst = tid * 8;
  const int swr = ((quad ^ ((fr >> 1) & 3)) * 8);

  f32x4 acc[8][4] = {};
  const int NT = K >> 6;  // K-tiles of 64

#define STA(p, kh, kt)                                              \
  {                                                                 \
    int o = ((p) * 2 + (kh)) * 8192 + ldst;                         \
    gload16(pAst + (kt) * 64 + (kh) * 32, &sA[o]);                  \
    gload16(pAst + h128a + (kt) * 64 + (kh) * 32, &sA[o + 4096]);   \
  }
#define STW(p, kh, kt)                                              \
  {                                                                 \
    int o = ((p) * 2 + (kh)) * 8192 + ldst;                         \
    gload16(pWst + (kt) * 64 + (kh) * 32, &sW[o]);                  \
    gload16(pWst + h128w + (kt) * 64 + (kh) * 32, &sW[o + 4096]);   \
  }
#define LDB(p, kk)                                                  \
  _Pragma("unroll") for (int j = 0; j < 4; ++j) {                   \
    int rn = wn * 64 + j * 16 + fr;                                 \
    bf[j] = *(const f16x8*)&sW[((p) * 2 + (kk)) * 8192 + rn * 32 + swr]; \
  }
#define LDA(p, kk, mh)                                              \
  _Pragma("unroll") for (int i2 = 0; i2 < 4; ++i2) {                \
    int rm = wm * 128 + (mh) * 64 + i2 * 16 + fr;                   \
    af[i2] = *(const f16x8*)&sA[((p) * 2 + (kk)) * 8192 + rm * 32 + swr]; \
  }
#define DOMFMA(mh)                                                  \
  __builtin_amdgcn_s_setprio(1);                                    \
  _Pragma("unroll") for (int i2 = 0; i2 < 4; ++i2)                  \
  _Pragma("unroll") for (int j = 0; j < 4; ++j)                     \
      acc[(mh) * 4 + i2][j] = MFMA16(af[i2], bf[j], acc[(mh) * 4 + i2][j]); \
  __builtin_amdgcn_s_setprio(0);

  STA(0, 0, 0); STW(0, 0, 0); STA(0, 1, 0); STW(0, 1, 0);

  for (int t = 0; t < NT; ++t) {
    const int p = t & 1, pn = p ^ 1;
    const bool pf = (t + 1 < NT);
    f16x8 af[4], bf[4];
    if (t == NT - 1) { WAIT_VM(0); } else { WAIT_VM(4); }
    SBAR;
    if (pf) STA(pn, 0, t + 1);
    LDB(p, 0); LDA(p, 0, 0);
    DOMFMA(0);
    SBAR;
    if (pf) STW(pn, 0, t + 1);
    LDA(p, 0, 1);
    DOMFMA(1);
    if (t == NT - 1) { WAIT_VM(0); } else { WAIT_VM(4); }
    SBAR;
    if (pf) STA(pn, 1, t + 1);
    LDB(p, 1); LDA(p, 1, 0);
    DOMFMA(0);
    SBAR;
    if (pf) STW(pn, 1, t + 1);
    LDA(p, 1, 1);
    DOMFMA(1);
  }
#undef STA
#undef STW
#undef LDB
#undef LDA
#undef DOMFMA

  // C/D map: col = lane&15, row = quad*4 + reg
  bool is_h1 = true;
  const float* bp = bias;
  int nb0 = n0;
  if (EPI == 1) {
    is_h1 = (n0 < 2048);
    bp = is_h1 ? bias : bias2;
    nb0 = is_h1 ? n0 : n0 - 2048;
  }
#pragma unroll
  for (int j = 0; j < 4; ++j) {
    int n = nb0 + wn * 64 + j * 16 + fr;
    float bv = bp[n];
#pragma unroll
    for (int i = 0; i < 8; ++i) {
      int mb = m0 + wm * 128 + i * 16 + quad * 4;
#pragma unroll
      for (int r = 0; r < 4; ++r) {
        int m = mb + r;
        float v = fmaxf(acc[i][j][r] + bv, 0.0f);
        if (is_h1)
          Ch[(size_t)m * HDIM + n] = (f16)v;
        else
          Cf[(size_t)m * LDIM + n] = (f16)v;
      }
    }
  }
}

// ============================================================================
// 8-phase 128(M)x384(N) fp16 GEMM — best measured for short-K dispatches
// (delta K=512, base K=1024): full 256-block coverage. Same schedule family.
// EPI: 0 = PACKED fp16 C ([m/4][N][4]) + bias
//      3 = delta-xg: PACKED fp16 C = acc + Xb (packed xg_base, NO bias)
// ============================================================================
template <int EPI>
__global__ __launch_bounds__(512, 1) void gemm_384(
    const f16* __restrict__ A, const f16* __restrict__ W,
    const float* __restrict__ bias,
    const f16* __restrict__ Xb,
    f16* __restrict__ Ch, int N, int K, int lda, int ldw) {
  __shared__ f16 sA[2 * 2 * 128 * 32];  // 32 KB
  __shared__ f16 sW[2 * 2 * 384 * 32];  // 96 KB
  const int tid = threadIdx.x;
  const int w = tid >> 6, lane = tid & 63;
  const int wm = w >> 2, wn = w & 3;
  const int fr = lane & 15, quad = lane >> 4;
  const int nb = N / 384;  // 8
  const int m0 = (blockIdx.x / nb) * 128, n0 = (blockIdx.x % nb) * 384;

  const int swz_src = (((tid & 3) ^ ((tid >> 3) & 3)) * 8);
  const f16* pAst = A + (size_t)(m0 + (tid >> 2)) * lda + swz_src;
  const f16* pWst = W + (size_t)(n0 + (tid >> 2)) * ldw + swz_src;
  const size_t h128w = (size_t)128 * ldw;
  const int swr = ((quad ^ ((fr >> 1) & 3)) * 8);

  f32x4 acc[4][6] = {};
  const int NT = K >> 6;  // K-tiles of 64

#define STA(p, kh, kt)                                                \
  {                                                                   \
    int o = ((p) * 2 + (kh)) * 4096 + tid * 8;                        \
    gload16(pAst + (kt) * 64 + (kh) * 32, &sA[o]);                    \
  }
#define STW(p, kh, kt)                                                \
  {                                                                   \
    int o = ((p) * 2 + (kh)) * 12288 + tid * 8;                       \
    gload16(pWst + (kt) * 64 + (kh) * 32, &sW[o]);                    \
    gload16(pWst + h128w + (kt) * 64 + (kh) * 32, &sW[o + 4096]);     \
    gload16(pWst + 2 * h128w + (kt) * 64 + (kh) * 32, &sW[o + 8192]); \
  }
#define LDA(p, kk)                                                    \
  _Pragma("unroll") for (int i2 = 0; i2 < 4; ++i2) {                  \
    int rm = wm * 64 + i2 * 16 + fr;                                  \
    af[i2] = *(const f16x8*)&sA[((p) * 2 + (kk)) * 4096 + rm * 32 + swr]; \
  }
#define LDB(p, kk, nh)                                                \
  _Pragma("unroll") for (int j2 = 0; j2 < 3; ++j2) {                  \
    int rn = wn * 96 + ((nh) * 3 + j2) * 16 + fr;                     \
    bf[j2] = *(const f16x8*)&sW[((p) * 2 + (kk)) * 12288 + rn * 32 + swr]; \
  }
#define DOMFMA(nh)                                                    \
  __builtin_amdgcn_s_setprio(1);                                      \
  _Pragma("unroll") for (int i2 = 0; i2 < 4; ++i2)                    \
  _Pragma("unroll") for (int j2 = 0; j2 < 3; ++j2)                    \
      acc[i2][(nh) * 3 + j2] = MFMA16(af[i2], bf[j2], acc[i2][(nh) * 3 + j2]); \
  __builtin_amdgcn_s_setprio(0);

  STA(0, 0, 0); STW(0, 0, 0); STA(0, 1, 0); STW(0, 1, 0);

  for (int t = 0; t < NT; ++t) {
    const int p = t & 1, pn = p ^ 1;
    const bool pf = (t + 1 < NT);
    f16x8 af[4], bf[3];
    if (t == NT - 1) { WAIT_VM(0); } else { WAIT_VM(4); }
    SBAR;
    if (pf) STA(pn, 0, t + 1);
    LDA(p, 0); LDB(p, 0, 0);
    DOMFMA(0);
    SBAR;
    if (pf) STW(pn, 0, t + 1);
    LDB(p, 0, 1);
    DOMFMA(1);
    if (t == NT - 1) { WAIT_VM(0); } else { WAIT_VM(4); }
    SBAR;
    if (pf) STA(pn, 1, t + 1);
    LDA(p, 1); LDB(p, 1, 0);
    DOMFMA(0);
    SBAR;
    if (pf) STW(pn, 1, t + 1);
    LDB(p, 1, 1);
    DOMFMA(1);
  }
#undef STA
#undef STW
#undef LDA
#undef LDB
#undef DOMFMA

#pragma unroll
  for (int j = 0; j < 6; ++j) {
    int n = n0 + wn * 96 + j * 16 + fr;
    float bv = (EPI == 3) ? 0.0f : bias[n];
#pragma unroll
    for (int i = 0; i < 4; ++i) {
      int mb = m0 + wm * 64 + i * 16 + quad * 4;
      if (EPI == 0) {
        f16x4 o = {(f16)(acc[i][j][0] + bv), (f16)(acc[i][j][1] + bv),
                   (f16)(acc[i][j][2] + bv), (f16)(acc[i][j][3] + bv)};
        *(f16x4*)&Ch[((size_t)(mb >> 2) * N + n) * 4] = o;
      } else {
        size_t off = ((size_t)(mb >> 2) * N + n) * 4;
        f16x4 b4 = *(const f16x4*)&Xb[off];
        f16x4 o = {(f16)(acc[i][j][0] + (float)b4[0]),
                   (f16)(acc[i][j][1] + (float)b4[1]),
                   (f16)(acc[i][j][2] + (float)b4[2]),
                   (f16)(acc[i][j][3] + (float)b4[3])};
        *(f16x4*)&Ch[off] = o;
      }
    }
  }
}

// ============================================================================
// Logits GEMM (N=512, K=2048): 128(M)x64(N) tile -> grid 8x32 = 256 blocks
// at 2/CU. 256 threads, 4 waves; wave = 32Mx64N, acc[2][4]. Triple-buffer.
// fp32 out + tanh -> fp16 into J0 ans cols (cols 1024:1536, stride JDIM).
// ============================================================================
__global__ __launch_bounds__(256, 2) void gemm_logits(
    const f16* __restrict__ A, const f16* __restrict__ W,
    const float* __restrict__ bias, float* __restrict__ Cout,
    f16* __restrict__ aJH, int N, int K) {
  __shared__ f16 sA[3][128 * 32];  // 24 KB
  __shared__ f16 sW[3][64 * 32];   // 12 KB
  const int tid = threadIdx.x;
  const int w = tid >> 6, lane = tid & 63;
  const int fr = lane & 15, quad = lane >> 4;
  const int m0 = blockIdx.y * 128, n0 = blockIdx.x * 64;
  const int swz_src = (((tid & 3) ^ ((tid >> 3) & 3)) * 8);
  const f16* pA = A + (size_t)(m0 + (tid >> 2)) * K + swz_src;
  const f16* pW = W + (size_t)(n0 + (tid >> 2)) * K + swz_src;
  const size_t rstep = (size_t)64 * K;
  const int swr = ((quad ^ ((fr >> 1) & 3)) * 8);

  f32x4 acc[2][4] = {};
  const int NT = K >> 5;

  auto stage = [&](int b, int k) {
    gload16(pA + k, &sA[b][tid * 8]);
    gload16(pA + rstep + k, &sA[b][tid * 8 + 2048]);
    gload16(pW + k, &sW[b][tid * 8]);
  };
  stage(0, 0);
  stage(1, 32);
  int bb = 0;
  for (int t = 0; t < NT; ++t) {
    if (t == NT - 1) { WAIT_VM(0); } else { WAIT_VM(3); }
    __builtin_amdgcn_s_barrier();
    if (t + 2 < NT) {
      int bn = bb + 2; if (bn >= 3) bn -= 3;
      stage(bn, (t + 2) * 32);
    }
    f16x8 af[2], bf[4];
#pragma unroll
    for (int i = 0; i < 2; ++i) {
      int rm = w * 32 + i * 16 + fr;
      af[i] = *(const f16x8*)&sA[bb][rm * 32 + swr];
    }
#pragma unroll
    for (int j = 0; j < 4; ++j) {
      int rn = j * 16 + fr;
      bf[j] = *(const f16x8*)&sW[bb][rn * 32 + swr];
    }
    __builtin_amdgcn_s_setprio(1);
#pragma unroll
    for (int i = 0; i < 2; ++i)
#pragma unroll
      for (int j = 0; j < 4; ++j) acc[i][j] = MFMA16(af[i], bf[j], acc[i][j]);
    __builtin_amdgcn_s_setprio(0);
    if (++bb == 3) bb = 0;
  }

#pragma unroll
  for (int j = 0; j < 4; ++j) {
    int n = n0 + j * 16 + fr;
    float bv = bias[n];
#pragma unroll
    for (int i = 0; i < 2; ++i) {
      int mb = m0 + w * 32 + i * 16 + quad * 4;
#pragma unroll
      for (int r = 0; r < 4; ++r) {
        int m = mb + r;
        float v = acc[i][j][r] + bv;
        Cout[(size_t)m * N + n] = v;
        aJH[(size_t)m * JDIM + 1024 + n] = (f16)fast_tanh(v);
      }
    }
  }
}

// ============================================================================
// Fused GRU cycle, RETILED: 512 threads, M=128 x N=128-per-gate.
// Grid = 32(m) x 8(n) = 256 blocks (1/CU, 8 waves). AI 96 vs old 76.8;
// 24 MFMA per barrier-pair (2x old); staging exactly 1 load/thread/operand
// (4/step -> vmcnt(4)). bid&7 = n-block = XCD: W_hh slice (768KB) L2-resident
// across all 32 dispatches. Triple-buffer LDS 96KB; same swizzle family
// (row = tid>>2 -> source chunk (tid&3)^((tid>>3)&3), read (quad^((row>>1)&3))).
// State in cols [0,1024) of J [B,1536]; xg PACKED [m/4][3072][4].
// Wave layout: wm=w>>2 (64-row half), wn=w&3 (32-col quarter); per gate
// acc[4][2] frags (row i=0..3, col j=0..1).
// ============================================================================
__global__ __launch_bounds__(512, 1) void gru_fused(
    const f16* __restrict__ inJ, const f16* __restrict__ Whh,
    const float* __restrict__ bhh, const f16* __restrict__ xgP,
    f16* __restrict__ outJ) {
  __shared__ f16 sA[3][128 * 32];   // 24 KB
  __shared__ f16 sW0[3][128 * 32];  // 24 KB
  __shared__ f16 sW1[3][128 * 32];
  __shared__ f16 sW2[3][128 * 32];
  const int tid = threadIdx.x;
  const int w = tid >> 6, lane = tid & 63;
  const int fr = lane & 15, quad = lane >> 4;
  const int wm = w >> 2, wn = w & 3;
  const int n0 = (blockIdx.x & 7) * 128;   // XCD-resident W slice
  const int m0 = (blockIdx.x >> 3) * 128;
  const int swz_src = (((tid & 3) ^ ((tid >> 3) & 3)) * 8);
  const f16* pA = inJ + (size_t)(m0 + (tid >> 2)) * JDIM + swz_src;
  const f16* pW0 = Whh + (size_t)(n0 + (tid >> 2)) * LDIM + swz_src;
  const f16* pW1 = pW0 + (size_t)LDIM * LDIM;
  const f16* pW2 = pW1 + (size_t)LDIM * LDIM;
  const int swr = ((quad ^ ((fr >> 1) & 3)) * 8);

  f32x4 ar[4][2] = {}, az[4][2] = {}, an_[4][2] = {};
  const int NT = LDIM >> 5;  // 32 K-steps of 32

  auto stage = [&](int b, int k) {
    gload16(pA + k, &sA[b][tid * 8]);
    gload16(pW0 + k, &sW0[b][tid * 8]);
    gload16(pW1 + k, &sW1[b][tid * 8]);
    gload16(pW2 + k, &sW2[b][tid * 8]);
  };
  stage(0, 0);
  stage(1, 32);
  int bb = 0;
  for (int t = 0; t < NT; ++t) {
    if (t == NT - 1) { WAIT_VM(0); } else { WAIT_VM(4); }
    __builtin_amdgcn_s_barrier();
    if (t + 2 < NT) {
      int bn = bb + 2; if (bn >= 3) bn -= 3;
      stage(bn, (t + 2) * 32);
    }
    f16x8 a_[4], w0[2], w1[2], w2[2];
#pragma unroll
    for (int i = 0; i < 4; ++i) {
      int rr = wm * 64 + i * 16 + fr;
      a_[i] = *(const f16x8*)&sA[bb][rr * 32 + ((quad ^ ((rr >> 1) & 3)) << 3)];
    }
#pragma unroll
    for (int j = 0; j < 2; ++j) {
      int rw = wn * 32 + j * 16 + fr;
      int wo = rw * 32 + ((quad ^ ((rw >> 1) & 3)) << 3);
      w0[j] = *(const f16x8*)&sW0[bb][wo];
      w1[j] = *(const f16x8*)&sW1[bb][wo];
      w2[j] = *(const f16x8*)&sW2[bb][wo];
    }
    __builtin_amdgcn_s_setprio(1);
#pragma unroll
    for (int i = 0; i < 4; ++i)
#pragma unroll
      for (int j = 0; j < 2; ++j) {
        ar[i][j] = MFMA16(a_[i], w0[j], ar[i][j]);
        az[i][j] = MFMA16(a_[i], w1[j], az[i][j]);
        an_[i][j] = MFMA16(a_[i], w2[j], an_[i][j]);
      }
    __builtin_amdgcn_s_setprio(0);
    if (++bb == 3) bb = 0;
  }

  // epilogue: full GRU gate update; xg loads are f16x4 (packed layout)
#pragma unroll
  for (int j = 0; j < 2; ++j) {
    int col = n0 + wn * 32 + j * 16 + fr;
    float br = bhh[col], bz = bhh[col + LDIM], bn = bhh[col + 2 * LDIM];
#pragma unroll
    for (int i = 0; i < 4; ++i) {
      int mb = m0 + wm * 64 + i * 16 + quad * 4;
      size_t xb = ((size_t)(mb >> 2) * GDIM + col) * 4;
      f16x4 x4r = *(const f16x4*)&xgP[xb];
      f16x4 x4z = *(const f16x4*)&xgP[xb + (size_t)LDIM * 4];
      f16x4 x4n = *(const f16x4*)&xgP[xb + (size_t)2 * LDIM * 4];
#pragma unroll
      for (int r = 0; r < 4; ++r) {
        int m = mb + r;
        size_t si = (size_t)m * JDIM + col;
        float sold = (float)inJ[si];
        float rg = fast_sigmoid((float)x4r[r] + ar[i][j][r] + br);
        float zg = fast_sigmoid((float)x4z[r] + az[i][j][r] + bz);
        float ng = fast_tanh((float)x4n[r] + rg * (an_[i][j][r] + bn));
        float o = (1.0f - zg) * ng + zg * sold;
        outJ[si] = (f16)o;
      }
    }
  }
}

// halt = h2[B,1024](f16) @ hw2[2,1024]^T + hb2; one wave per row.
__global__ __launch_bounds__(256) void halt_kernel(
    const f16* __restrict__ h2, const float* __restrict__ hw2,
    const float* __restrict__ hb2, float* __restrict__ out) {
  int wave = (blockIdx.x * 256 + threadIdx.x) >> 6;
  int lane = threadIdx.x & 63;
  if (wave >= BATCH) return;
  const f16* row = h2 + (size_t)wave * LDIM;
  float s0 = 0.0f, s1 = 0.0f;
#pragma unroll
  for (int k = lane; k < LDIM; k += 64) {
    float v = (float)row[k];
    s0 = fmaf(v, hw2[k], s0);
    s1 = fmaf(v, hw2[LDIM + k], s1);
  }
#pragma unroll
  for (int off = 32; off > 0; off >>= 1) {
    s0 += __shfl_xor(s0, off);
    s1 += __shfl_xor(s1, off);
  }
  if (lane == 0) {
    out[(size_t)wave * 2 + 0] = s0 + hb2[0];
    out[(size_t)wave * 2 + 1] = s1 + hb2[1];
  }
}

extern "C" void kernel_launch(void* const* d_in, const int* in_sizes, int n_in,
                              void* d_out, int out_size, void* d_ws, size_t ws_size,
                              hipStream_t stream) {
  const float* inputs = (const float*)d_in[0];
  const float* W_ih = (const float*)d_in[1];
  const float* W_hh = (const float*)d_in[2];
  const float* b_ih = (const float*)d_in[3];
  const float* b_hh = (const float*)d_in[4];
  const float* aw1 = (const float*)d_in[5];
  const float* ab1 = (const float*)d_in[6];
  const float* aw2 = (const float*)d_in[7];
  const float* ab2 = (const float*)d_in[8];
  const float* hw1 = (const float*)d_in[9];
  const float* hb1 = (const float*)d_in[10];
  const float* hw2 = (const float*)d_in[11];
  const float* hb2 = (const float*)d_in[12];

  float* out = (float*)d_out;
  float* logits_out = out;                               // [8, B, 512]
  float* halt_out = out + (size_t)OUTER * BATCH * ODIM;  // [8, B, 2]

  char* p = (char*)d_ws;
  auto take = [&](size_t bytes) { char* q = p; p += (bytes + 255) & ~255ull; return q; };
  // xg union region (25.2 MB): holds {inpF16 [B,1024] + WihF [3072,1536]}
  // during setup/base-GEMM; becomes xg (packed delta result) / h1 overlay
  // during the step loop. xgBase is never overlaid.
  f16* xg = (f16*)take((size_t)BATCH * GDIM * 2);
  f16* inpF16 = xg;                                   // [B,1024] f16 (setup)
  f16* WihF = xg + (size_t)BATCH * LDIM;              // [3072,1536] f16 (setup)
  f16* xgBase = (f16*)take((size_t)BATCH * GDIM * 2); // 25.2 MB, PACKED
  f16* J0 = (f16*)take((size_t)BATCH * JDIM * 2);     // [B,1536] joint
  f16* J1 = (f16*)take((size_t)BATCH * JDIM * 2);
  f16* h2F = (f16*)take((size_t)BATCH * LDIM * 2);    // h2 f16 [B,1024]
  f16* WhhF = (f16*)take((size_t)GDIM * LDIM * 2);
  f16* WjF = (f16*)take((size_t)(HDIM + LDIM) * JDIM * 2);  // [aw1; hw1]
  f16* aw2F = (f16*)take((size_t)ODIM * HDIM * 2);
  f16* W2F = (f16*)take((size_t)GDIM * 512 * 2);      // W_ih[:,1024:1536]
  f16* h1 = xg;                                        // overlay (see above)
  if ((size_t)(p - (char*)d_ws) > ws_size) return;     // workspace guard

  (void)hipMemsetAsync(J0, 0, (size_t)BATCH * JDIM * 2, stream);

  auto conv = [&](const float* s, f16* d, size_t n) {
    int n4 = (int)(n / 4);
    convert_w<<<(n4 + 255) / 256, 256, 0, stream>>>(s, d, n4);
  };
  conv(inputs, inpF16, (size_t)BATCH * LDIM);
  conv(W_ih, WihF, (size_t)GDIM * JDIM);
  convert_w2<<<(GDIM * 128 + 255) / 256, 256, 0, stream>>>(W_ih, W2F);
  conv(W_hh, WhhF, (size_t)GDIM * LDIM);
  conv(aw1, WjF, (size_t)HDIM * JDIM);
  conv(hw1, WjF + (size_t)HDIM * JDIM, (size_t)LDIM * JDIM);
  conv(aw2, aw2F, (size_t)ODIM * HDIM);

  // xg_base = inputs @ W1^T + b_ih (K=1024; W1 = W_ih[:, :1024], row stride
  // JDIM). Computed ONCE. PACKED.
  gemm_384<0><<<(BATCH / 128) * (GDIM / 384), 512, 0, stream>>>(
      inpF16, WihF, b_ih, nullptr, xgBase, GDIM, LDIM, LDIM, JDIM);

  for (int s = 0; s < OUTER; ++s) {
    // xg = xg_base + ans @ W2^T (K=512 delta; skipped at s=0: ans=0).
    // A = J0 ans cols (row stride JDIM).
    const f16* xgUse = xgBase;
    if (s > 0) {
      gemm_384<3><<<(BATCH / 128) * (GDIM / 384), 512, 0, stream>>>(
          J0 + 1024, W2F, nullptr, xgBase, xg, GDIM, 512, JDIM, 512);
      xgUse = xg;
    }
    // 4 fused GRU cycles on joint ping-pong; c3 lands state back in J0
    gru_fused<<<256, 512, 0, stream>>>(J0, WhhF, b_hh, xgUse, J1);
    gru_fused<<<256, 512, 0, stream>>>(J1, WhhF, b_hh, xgUse, J0);
    gru_fused<<<256, 512, 0, stream>>>(J0, WhhF, b_hh, xgUse, J1);
    gru_fused<<<256, 512, 0, stream>>>(J1, WhhF, b_hh, xgUse, J0);
    // h1 = relu(joint @ aw1^T + ab1) f16 (overlay xg);
    // h2 = relu(joint @ hw1^T + hb1) f16 — one combined N=3072 GEMM (256² tile)
    gemm_256<1><<<(BATCH / 256) * ((HDIM + LDIM) / 256), 512, 0, stream>>>(
        J0, WjF, ab1, hb1, nullptr, h1, h2F, HDIM + LDIM, JDIM, JDIM, JDIM);
    // logits = h1 @ aw2^T + ab2 -> out; ans = tanh -> J0 ans cols
    gemm_logits<<<dim3(ODIM / 64, BATCH / 128), 256, 0, stream>>>(
        h1, aw2F, ab2, logits_out + (size_t)s * BATCH * ODIM, J0, ODIM, HDIM);
    // halt = h2 @ hw2^T + hb2 -> out
    halt_kernel<<<BATCH / 4, 256, 0, stream>>>(
        h2F, hw2, hb2, halt_out + (size_t)s * BATCH * 2);
  }
}